// Round 4
// baseline (259.592 us; speedup 1.0000x reference)
//
#include <hip/hip_runtime.h>

typedef __attribute__((ext_vector_type(4))) float f32x4;

#define NB 16384
#define ND 32
#define NK 128

// ---------------------------------------------------------------------------
// Kernel 1: raw per-cluster scatter M = sum_b x x^T (lower-tri, rect-packed
// 4-row strips) + column sums S, for a 64-k tile and a 128-sample chunk.
// grid = 256 (ktile = bx&1, chunk = bx>>1), block = 256.
// Double-buffered LDS staging, one barrier per 2-sample iteration.
// Per-block partial layout: [608][64] floats at part + blockIdx*38912
//   vidx 0..575  : strips R=0..7, strip R at 8R(R+1), entry (r,c) = r*4(R+1)+c
//   vidx 576+d   : column sum for dim d
// ---------------------------------------------------------------------------
template<int SP>
__device__ __forceinline__ void k1_body(const float* __restrict__ x,
                                        float* __restrict__ part,
                                        float* __restrict__ vs,
                                        int k0, int b0, int t) {
  constexpr int CL = 4*(SP+1);   // cols of low strip  R=SP
  constexpr int CH = 4*(8-SP);   // cols of high strip R=7-SP
  const int sd = t >> 3, sj = t & 7;   // staging: row d, float4-group
  const int kl = t & 63;               // compute: local k

  float aL[4][CL];
  float aH[4][CH];
  float ssum[8];
  #pragma unroll
  for (int r=0;r<4;r++){
    #pragma unroll
    for (int c=0;c<CL;c++) aL[r][c]=0.f;
    #pragma unroll
    for (int c=0;c<CH;c++) aH[r][c]=0.f;
  }
  #pragma unroll
  for (int i=0;i<8;i++) ssum[i]=0.f;

  const float* src0 = x + ((size_t)b0*ND + sd)*NK + k0 + 4*sj;

  f32x4 rc[2][2], rn[2][2];
  #pragma unroll
  for (int s=0;s<2;s++){
    const float* src = src0 + (size_t)s*4096;
    rc[s][0] = *(const f32x4*)src;
    rc[s][1] = *(const f32x4*)(src+32);
  }

  for (int g=0; g<64; ++g) {
    // issue next pair's loads early (overlap with LDS writes + compute)
    if (g < 63) {
      #pragma unroll
      for (int s=0;s<2;s++){
        const float* src = src0 + (size_t)(2*(g+1)+s)*4096;
        rn[s][0] = *(const f32x4*)src;
        rn[s][1] = *(const f32x4*)(src+32);
      }
    }
    // stage current pair into buffer g&1 (transposed [k][36]) + column sums
    float* dstbuf = vs + (g&1)*4608;
    #pragma unroll
    for (int s=0;s<2;s++){
      float* dst = dstbuf + s*2304;
      #pragma unroll
      for (int i=0;i<4;i++){
        dst[(4*sj+i)*36 + sd]    = rc[s][0][i];
        dst[(4*sj+32+i)*36 + sd] = rc[s][1][i];
        ssum[i]   += rc[s][0][i];
        ssum[4+i] += rc[s][1][i];
      }
    }
    __syncthreads();
    // compute from buffer g&1
    #pragma unroll
    for (int s=0;s<2;s++){
      const float* row = dstbuf + s*2304 + kl*36;
      f32x4 bv[8-SP];
      #pragma unroll
      for (int q=0;q<8-SP;q++) bv[q] = *(const f32x4*)(row + 4*q);
      #pragma unroll
      for (int r=0;r<4;r++){
        const float al = bv[SP][r];     // v[k][4*SP+r]
        const float ah = bv[7-SP][r];   // v[k][4*(7-SP)+r]
        #pragma unroll
        for (int q=0;q<=SP;q++){
          #pragma unroll
          for (int i=0;i<4;i++) aL[r][4*q+i] += al*bv[q][i];
        }
        #pragma unroll
        for (int q=0;q<8-SP;q++){
          #pragma unroll
          for (int i=0;i<4;i++) aH[r][4*q+i] += ah*bv[q][i];
        }
      }
    }
    #pragma unroll
    for (int s=0;s<2;s++){ rc[s][0]=rn[s][0]; rc[s][1]=rn[s][1]; }
  }

  float* pb = part + (size_t)blockIdx.x*38912;
  #pragma unroll
  for (int r=0;r<4;r++){
    #pragma unroll
    for (int c=0;c<CL;c++)
      pb[(8*SP*(SP+1) + r*CL + c)*64 + kl] = aL[r][c];
    #pragma unroll
    for (int c=0;c<CH;c++)
      pb[(8*(7-SP)*(8-SP) + r*CH + c)*64 + kl] = aH[r][c];
  }
  #pragma unroll
  for (int i=0;i<4;i++){
    pb[(576+sd)*64 + 4*sj + i]      = ssum[i];
    pb[(576+sd)*64 + 32 + 4*sj + i] = ssum[4+i];
  }
}

__global__ __launch_bounds__(256, 2) void k1_scatter(const float* __restrict__ x,
                                                     float* __restrict__ part) {
  __shared__ float vs[2*4608];   // 2 buffers x 2 samples x [64 k][36]
  const int t = threadIdx.x;
  const int ktile = blockIdx.x & 1;
  const int chunk = blockIdx.x >> 1;     // 0..127
  const int k0 = ktile*64, b0 = chunk*128;
  switch (t>>6) {  // wave-uniform
    case 0:  k1_body<0>(x, part, vs, k0, b0, t); break;
    case 1:  k1_body<1>(x, part, vs, k0, b0, t); break;
    case 2:  k1_body<2>(x, part, vs, k0, b0, t); break;
    default: k1_body<3>(x, part, vs, k0, b0, t); break;
  }
}

// ---------------------------------------------------------------------------
// Kernel 2a: reduce 64-chunk halves of partials.  grid 608 (2 halves x 2
// ktiles x 152 vgroups), block 256.
// k1 block for (ktile, chunk) is chunk*2 + ktile  ->  stride 2*38912 per chunk.
// out sfin[h][608][128]
// ---------------------------------------------------------------------------
__global__ void k2a_reduce(const float* __restrict__ part, float* __restrict__ sfin) {
  const int t = threadIdx.x;
  const int bx = blockIdx.x;
  const int h = bx & 1, ktile = (bx>>1)&1, vg = bx>>2;
  const int vidx = vg*4 + (t>>6);
  const int kl = t & 63;
  // chunks h*64 .. h*64+63 of this ktile
  const float* p = part + ((size_t)(h*64)*2 + ktile)*38912 + vidx*64 + kl;
  float a0=0.f,a1=0.f,a2=0.f,a3=0.f;
  for (int c=0;c<64;c+=4){
    a0 += p[(size_t)(c+0)*77824];
    a1 += p[(size_t)(c+1)*77824];
    a2 += p[(size_t)(c+2)*77824];
    a3 += p[(size_t)(c+3)*77824];
  }
  sfin[h*77824 + vidx*128 + ktile*64 + kl] = (a0+a1)+(a2+a3);
}

// ---------------------------------------------------------------------------
// Kernel 2b: per-cluster cov assembly + Cholesky.  grid 128, block 256.
// Writes row-padded L (rows padded to mult-of-4, zeros) + inv-diag to ws,
// and new_mu[d][K] to ws.
// ---------------------------------------------------------------------------
__global__ void k2b_chol(const float* __restrict__ sfin,
                         const float* __restrict__ mu0,
                         const float* __restrict__ L0,
                         const float* __restrict__ n0p,
                         float* __restrict__ lpad,
                         float* __restrict__ nmu) {
  const int k = blockIdx.x;
  const int t = threadIdx.x;
  __shared__ float L0s[32*33];
  __shared__ float Am[32*33];
  __shared__ float xdl[32];
  __shared__ float dinv[32];
  const float n0 = n0p[0];
  const float denom = n0 + (float)NB;

  for (int idx = t; idx < 1024; idx += 256)
    L0s[(idx>>5)*33 + (idx&31)] = L0[k*1024 + idx];
  if (t < 32) {
    const float S  = sfin[(576+t)*128 + k] + sfin[77824 + (576+t)*128 + k];
    const float m0 = mu0[t*128 + k];
    nmu[t*128 + k] = (n0*m0 + S) / denom;          // B*x_mu == S
    xdl[t] = S*(1.0f/NB) - m0;
  }
  __syncthreads();

  const float c1 = n0/denom, c2 = 1.0f/denom;
  const float c3 = n0*(float)NB/(denom*denom);
  for (int idx = t; idx < 1024; idx += 256) {
    const int d = idx>>5, e = idx&31;
    const int dd = d>=e?d:e, ee = d>=e?e:d;
    const int R = dd>>2;
    const int vi = 8*R*(R+1) + (dd&3)*4*(R+1) + ee;
    const float M  = sfin[vi*128 + k]      + sfin[77824 + vi*128 + k];
    const float Sd = sfin[(576+d)*128 + k] + sfin[77824 + (576+d)*128 + k];
    const float Se = sfin[(576+e)*128 + k] + sfin[77824 + (576+e)*128 + k];
    const float C = M - Sd*Se*(1.0f/NB);
    float g = 0.f;
    #pragma unroll 8
    for (int f=0; f<32; f++) g += L0s[d*33+f]*L0s[e*33+f];
    float a = g*c1 + C*c2 + xdl[d]*xdl[e]*c3;
    if (d==e) a += 1.0f;
    Am[d*33+e] = a;
  }
  __syncthreads();

  for (int j=0;j<32;j++){
    float acc = 0.f;
    if (t < 32 && t >= j) {
      acc = Am[t*33+j];
      for (int e=0;e<j;e++) acc -= Am[t*33+e]*Am[j*33+e];
    }
    __syncthreads();
    if (t == j) {
      const float dj = sqrtf(acc);
      Am[j*33+j] = dj;
      dinv[j] = 1.0f/dj;
    }
    __syncthreads();
    if (t < 32 && t > j) Am[t*33+j] = acc*dinv[j];
    __syncthreads();
  }

  if (t < 32) {
    const int d = t;
    int rs = 0;
    for (int e=0;e<d;e++) rs += (e+3)>>2;
    rs *= 4;
    const int rl = ((d+3)>>2)*4;
    float* lp = lpad + k*576;
    for (int e=0;e<rl;e++) lp[rs+e] = (e<d) ? Am[d*33+e] : 0.f;
    lp[544+d] = dinv[d];
  }
}

// ---------------------------------------------------------------------------
// Kernel 3 v3: whitening solve z = L^{-1}(x - mu').  grid 512, block 256.
// Block = 32-k tile x 128 samples; kl = t&31 -> every load/store covers full
// 128B lines.  XCD swizzle: ktile pair (2p, 2p+1) of the same chunk shares
// each 256B fetch granule -> both members placed on the SAME XCD
// (bx = 16*(u>>3) + 8*m + (u&7), u = 2*chunk+p; XCD = bx%8 = u&7 for both).
// Output written with nontemporal stores (no L2/L3 allocate).
// ---------------------------------------------------------------------------
__global__ __launch_bounds__(256, 2) void k3_whiten(const float* __restrict__ x,
                                                    const float* __restrict__ lpad,
                                                    const float* __restrict__ nmu,
                                                    float* __restrict__ out) {
  __shared__ float Lw[32*580];   // 32 k-rows, stride 580 (16B-aligned, mod32==4)
  __shared__ float muL[32*32];   // [d][kl]
  const int t = threadIdx.x;
  const int bx = blockIdx.x;     // 0..511
  const int m = (bx >> 3) & 1;
  const int u = ((bx >> 4) << 3) | (bx & 7);   // 0..255
  const int ktile = ((u & 1) << 1) | m;        // 2p + m
  const int chunk = u >> 1;                    // 0..127
  const int k0 = ktile*32;

  {
    const f32x4* src = (const f32x4*)(lpad + (size_t)k0*576);
    #pragma unroll
    for (int q=0;q<18;q++){
      const int idx = t + q*256;        // 4608 f32x4 = 32 rows x 144
      const int row = idx/144, col = idx - row*144;
      *(f32x4*)(&Lw[row*580 + col*4]) = src[idx];
    }
    #pragma unroll
    for (int idx=t; idx<1024; idx+=256)
      muL[idx] = nmu[(idx>>5)*128 + k0 + (idx&31)];
  }
  __syncthreads();

  const int kl = t & 31;
  const int so = t >> 5;          // 0..7 sample slot
  const float* Lrow = &Lw[kl*580];
  const int b0 = chunk*128;

  for (int it=0; it<4; ++it) {
    const int base = b0 + it*32 + so;
    const float* xa = x + (size_t)(base     )*4096 + k0 + kl;
    const float* xb = x + (size_t)(base +  8)*4096 + k0 + kl;
    const float* xc = x + (size_t)(base + 16)*4096 + k0 + kl;
    const float* xd = x + (size_t)(base + 24)*4096 + k0 + kl;
    float vA[32], vB[32], vC[32], vD[32];
    #pragma unroll
    for (int d=0; d<32; ++d) vA[d] = xa[d*128];
    #pragma unroll
    for (int d=0; d<32; ++d) vB[d] = xb[d*128];
    #pragma unroll
    for (int d=0; d<32; ++d) vC[d] = xc[d*128];
    #pragma unroll
    for (int d=0; d<32; ++d) vD[d] = xd[d*128];
    #pragma unroll
    for (int d=0; d<32; ++d) {
      const float m2 = muL[d*32 + kl];
      vA[d] -= m2; vB[d] -= m2; vC[d] -= m2; vD[d] -= m2;
    }
    int rs = 0;
    #pragma unroll
    for (int d=0; d<32; ++d) {
      float sA = vA[d], sB = vB[d], sC = vC[d], sD = vD[d];
      const int nq = (d+3)>>2;
      #pragma unroll
      for (int q=0; q<nq; ++q) {
        const f32x4 Lq = *(const f32x4*)(Lrow + rs + 4*q);
        sA -= Lq[0]*vA[4*q+0] + Lq[1]*vA[4*q+1] + Lq[2]*vA[4*q+2] + Lq[3]*vA[4*q+3];
        sB -= Lq[0]*vB[4*q+0] + Lq[1]*vB[4*q+1] + Lq[2]*vB[4*q+2] + Lq[3]*vB[4*q+3];
        sC -= Lq[0]*vC[4*q+0] + Lq[1]*vC[4*q+1] + Lq[2]*vC[4*q+2] + Lq[3]*vC[4*q+3];
        sD -= Lq[0]*vD[4*q+0] + Lq[1]*vD[4*q+1] + Lq[2]*vD[4*q+2] + Lq[3]*vD[4*q+3];
      }
      const float di = Lrow[544+d];
      vA[d] = sA*di; vB[d] = sB*di; vC[d] = sC*di; vD[d] = sD*di;
      rs += 4*nq;
    }
    float* oa = out + (size_t)(base     )*4096 + k0 + kl;
    float* ob = out + (size_t)(base +  8)*4096 + k0 + kl;
    float* oc = out + (size_t)(base + 16)*4096 + k0 + kl;
    float* od = out + (size_t)(base + 24)*4096 + k0 + kl;
    #pragma unroll
    for (int d=0; d<32; ++d) __builtin_nontemporal_store(vA[d], oa + d*128);
    #pragma unroll
    for (int d=0; d<32; ++d) __builtin_nontemporal_store(vB[d], ob + d*128);
    #pragma unroll
    for (int d=0; d<32; ++d) __builtin_nontemporal_store(vC[d], oc + d*128);
    #pragma unroll
    for (int d=0; d<32; ++d) __builtin_nontemporal_store(vD[d], od + d*128);
  }
}

// ---------------------------------------------------------------------------
extern "C" void kernel_launch(void* const* d_in, const int* in_sizes, int n_in,
                              void* d_out, int out_size, void* d_ws, size_t ws_size,
                              hipStream_t stream) {
  const float* x   = (const float*)d_in[0];
  const float* mu0 = (const float*)d_in[1];
  const float* L0  = (const float*)d_in[2];
  const float* n0  = (const float*)d_in[3];
  float* out  = (float*)d_out;
  float* part = out;                    // [256][608][64] = 9,961,472 floats (scratch in d_out)
  float* sfin = out + 20971520;         // [2][608][128]  = 155,648 floats  (scratch in d_out)
  float* lpad = (float*)d_ws;           // [128][576]
  float* nmu  = lpad + 128*576;         // [32][128]

  k1_scatter<<<256, 256, 0, stream>>>(x, part);
  k2a_reduce<<<608, 256, 0, stream>>>(part, sfin);
  k2b_chol  <<<128, 256, 0, stream>>>(sfin, mu0, L0, n0, lpad, nmu);
  k3_whiten <<<512, 256, 0, stream>>>(x, lpad, nmu, out);
}

// Round 5
// 227.795 us; speedup vs baseline: 1.1396x; 1.1396x over previous
//
#include <hip/hip_runtime.h>

typedef __attribute__((ext_vector_type(4))) float f32x4;

#define NB 16384
#define ND 32
#define NK 128

// ---------------------------------------------------------------------------
// Kernel 1: raw per-cluster scatter M = sum_b x x^T (lower-tri, rect-packed
// 4-row strips) + column sums S, for a 64-k tile and a 64-sample chunk.
// grid = 512 (ktile = bx&1, chunk = bx>>1), block = 256, 2 blocks/CU.
// Double-buffered LDS staging, ONE barrier per 2-sample iteration, register
// prefetch issued before the LDS writes. Partials stored nontemporal (keep
// x resident in L3 for k3).
// Per-block partial layout: [608][64] floats at part + blockIdx*38912
//   vidx 0..575  : strips R=0..7, strip R at 8R(R+1), entry (r,c) = r*4(R+1)+c
//   vidx 576+d   : column sum for dim d
// ---------------------------------------------------------------------------
template<int SP>
__device__ __forceinline__ void k1_body(const float* __restrict__ x,
                                        float* __restrict__ part,
                                        float* __restrict__ vs,
                                        int k0, int b0, int t) {
  constexpr int CL = 4*(SP+1);   // cols of low strip  R=SP
  constexpr int CH = 4*(8-SP);   // cols of high strip R=7-SP
  const int sd = t >> 3, sj = t & 7;   // staging: row d, float4-group
  const int kl = t & 63;               // compute: local k

  float aL[4][CL];
  float aH[4][CH];
  float ssum[8];
  #pragma unroll
  for (int r=0;r<4;r++){
    #pragma unroll
    for (int c=0;c<CL;c++) aL[r][c]=0.f;
    #pragma unroll
    for (int c=0;c<CH;c++) aH[r][c]=0.f;
  }
  #pragma unroll
  for (int i=0;i<8;i++) ssum[i]=0.f;

  const float* src0 = x + ((size_t)b0*ND + sd)*NK + k0 + 4*sj;

  f32x4 rc[2][2], rn[2][2];
  #pragma unroll
  for (int s=0;s<2;s++){
    const float* src = src0 + (size_t)s*4096;
    rc[s][0] = *(const f32x4*)src;
    rc[s][1] = *(const f32x4*)(src+32);
  }

  for (int g=0; g<32; ++g) {
    // issue next pair's loads early (latency overlaps LDS writes + compute)
    if (g < 31) {
      #pragma unroll
      for (int s=0;s<2;s++){
        const float* src = src0 + (size_t)(2*(g+1)+s)*4096;
        rn[s][0] = *(const f32x4*)src;
        rn[s][1] = *(const f32x4*)(src+32);
      }
    }
    // stage current pair into buffer g&1 (transposed [k][36]) + column sums
    float* dstbuf = vs + (g&1)*4608;
    #pragma unroll
    for (int s=0;s<2;s++){
      float* dst = dstbuf + s*2304;
      #pragma unroll
      for (int i=0;i<4;i++){
        dst[(4*sj+i)*36 + sd]    = rc[s][0][i];
        dst[(4*sj+32+i)*36 + sd] = rc[s][1][i];
        ssum[i]   += rc[s][0][i];
        ssum[4+i] += rc[s][1][i];
      }
    }
    __syncthreads();
    // compute from buffer g&1
    #pragma unroll
    for (int s=0;s<2;s++){
      const float* row = dstbuf + s*2304 + kl*36;
      f32x4 bv[8-SP];
      #pragma unroll
      for (int q=0;q<8-SP;q++) bv[q] = *(const f32x4*)(row + 4*q);
      #pragma unroll
      for (int r=0;r<4;r++){
        const float al = bv[SP][r];     // v[k][4*SP+r]
        const float ah = bv[7-SP][r];   // v[k][4*(7-SP)+r]
        #pragma unroll
        for (int q=0;q<=SP;q++){
          #pragma unroll
          for (int i=0;i<4;i++) aL[r][4*q+i] += al*bv[q][i];
        }
        #pragma unroll
        for (int q=0;q<8-SP;q++){
          #pragma unroll
          for (int i=0;i<4;i++) aH[r][4*q+i] += ah*bv[q][i];
        }
      }
    }
    #pragma unroll
    for (int s=0;s<2;s++){ rc[s][0]=rn[s][0]; rc[s][1]=rn[s][1]; }
  }

  float* pb = part + (size_t)blockIdx.x*38912;
  #pragma unroll
  for (int r=0;r<4;r++){
    #pragma unroll
    for (int c=0;c<CL;c++)
      __builtin_nontemporal_store(aL[r][c], &pb[(8*SP*(SP+1) + r*CL + c)*64 + kl]);
    #pragma unroll
    for (int c=0;c<CH;c++)
      __builtin_nontemporal_store(aH[r][c], &pb[(8*(7-SP)*(8-SP) + r*CH + c)*64 + kl]);
  }
  #pragma unroll
  for (int i=0;i<4;i++){
    __builtin_nontemporal_store(ssum[i],   &pb[(576+sd)*64 + 4*sj + i]);
    __builtin_nontemporal_store(ssum[4+i], &pb[(576+sd)*64 + 32 + 4*sj + i]);
  }
}

__global__ __launch_bounds__(256, 2) void k1_scatter(const float* __restrict__ x,
                                                     float* __restrict__ part) {
  __shared__ float vs[2*4608];   // 2 buffers x 2 samples x [64 k][36]
  const int t = threadIdx.x;
  const int ktile = blockIdx.x & 1;
  const int chunk = blockIdx.x >> 1;     // 0..255
  const int k0 = ktile*64, b0 = chunk*64;
  switch (t>>6) {  // wave-uniform
    case 0:  k1_body<0>(x, part, vs, k0, b0, t); break;
    case 1:  k1_body<1>(x, part, vs, k0, b0, t); break;
    case 2:  k1_body<2>(x, part, vs, k0, b0, t); break;
    default: k1_body<3>(x, part, vs, k0, b0, t); break;
  }
}

// ---------------------------------------------------------------------------
// Kernel 2a: reduce 128-chunk halves of partials.  grid 608 (2 halves x 2
// ktiles x 152 vgroups), block 256.  Nontemporal loads (don't evict x in L3).
// k1 block for (ktile, chunk) is chunk*2 + ktile  ->  stride 2*38912 per chunk.
// out sfin[h][608][128]
// ---------------------------------------------------------------------------
__global__ void k2a_reduce(const float* __restrict__ part, float* __restrict__ sfin) {
  const int t = threadIdx.x;
  const int bx = blockIdx.x;
  const int h = bx & 1, ktile = (bx>>1)&1, vg = bx>>2;
  const int vidx = vg*4 + (t>>6);
  const int kl = t & 63;
  // chunks h*128 .. h*128+127 of this ktile
  const float* p = part + ((size_t)(h*128)*2 + ktile)*38912 + vidx*64 + kl;
  float a0=0.f,a1=0.f,a2=0.f,a3=0.f;
  for (int c=0;c<128;c+=4){
    a0 += __builtin_nontemporal_load(&p[(size_t)(c+0)*77824]);
    a1 += __builtin_nontemporal_load(&p[(size_t)(c+1)*77824]);
    a2 += __builtin_nontemporal_load(&p[(size_t)(c+2)*77824]);
    a3 += __builtin_nontemporal_load(&p[(size_t)(c+3)*77824]);
  }
  sfin[h*77824 + vidx*128 + ktile*64 + kl] = (a0+a1)+(a2+a3);
}

// ---------------------------------------------------------------------------
// Kernel 2b: per-cluster cov assembly + Cholesky.  grid 128, block 256.
// Writes row-padded L (rows padded to mult-of-4, zeros) + inv-diag to ws,
// and new_mu[d][K] to ws.
// ---------------------------------------------------------------------------
__global__ void k2b_chol(const float* __restrict__ sfin,
                         const float* __restrict__ mu0,
                         const float* __restrict__ L0,
                         const float* __restrict__ n0p,
                         float* __restrict__ lpad,
                         float* __restrict__ nmu) {
  const int k = blockIdx.x;
  const int t = threadIdx.x;
  __shared__ float L0s[32*33];
  __shared__ float Am[32*33];
  __shared__ float xdl[32];
  __shared__ float dinv[32];
  const float n0 = n0p[0];
  const float denom = n0 + (float)NB;

  for (int idx = t; idx < 1024; idx += 256)
    L0s[(idx>>5)*33 + (idx&31)] = L0[k*1024 + idx];
  if (t < 32) {
    const float S  = sfin[(576+t)*128 + k] + sfin[77824 + (576+t)*128 + k];
    const float m0 = mu0[t*128 + k];
    nmu[t*128 + k] = (n0*m0 + S) / denom;          // B*x_mu == S
    xdl[t] = S*(1.0f/NB) - m0;
  }
  __syncthreads();

  const float c1 = n0/denom, c2 = 1.0f/denom;
  const float c3 = n0*(float)NB/(denom*denom);
  for (int idx = t; idx < 1024; idx += 256) {
    const int d = idx>>5, e = idx&31;
    const int dd = d>=e?d:e, ee = d>=e?e:d;
    const int R = dd>>2;
    const int vi = 8*R*(R+1) + (dd&3)*4*(R+1) + ee;
    const float M  = sfin[vi*128 + k]      + sfin[77824 + vi*128 + k];
    const float Sd = sfin[(576+d)*128 + k] + sfin[77824 + (576+d)*128 + k];
    const float Se = sfin[(576+e)*128 + k] + sfin[77824 + (576+e)*128 + k];
    const float C = M - Sd*Se*(1.0f/NB);
    float g = 0.f;
    #pragma unroll 8
    for (int f=0; f<32; f++) g += L0s[d*33+f]*L0s[e*33+f];
    float a = g*c1 + C*c2 + xdl[d]*xdl[e]*c3;
    if (d==e) a += 1.0f;
    Am[d*33+e] = a;
  }
  __syncthreads();

  for (int j=0;j<32;j++){
    float acc = 0.f;
    if (t < 32 && t >= j) {
      acc = Am[t*33+j];
      for (int e=0;e<j;e++) acc -= Am[t*33+e]*Am[j*33+e];
    }
    __syncthreads();
    if (t == j) {
      const float dj = sqrtf(acc);
      Am[j*33+j] = dj;
      dinv[j] = 1.0f/dj;
    }
    __syncthreads();
    if (t < 32 && t > j) Am[t*33+j] = acc*dinv[j];
    __syncthreads();
  }

  if (t < 32) {
    const int d = t;
    int rs = 0;
    for (int e=0;e<d;e++) rs += (e+3)>>2;
    rs *= 4;
    const int rl = ((d+3)>>2)*4;
    float* lp = lpad + k*576;
    for (int e=0;e<rl;e++) lp[rs+e] = (e<d) ? Am[d*33+e] : 0.f;
    lp[544+d] = dinv[d];
  }
}

// ---------------------------------------------------------------------------
// Kernel 3: whitening solve z = L^{-1}(x - mu').  grid 512, block 256.
// Block = 32-k tile x 128 samples; kl = t&31 -> every load/store covers full
// 128B lines.  XCD swizzle: ktile pair (2p, 2p+1) of the same chunk shares
// each 256B fetch granule -> both members placed on the SAME XCD.
// Output written with nontemporal stores (no L2/L3 allocate).
// ---------------------------------------------------------------------------
__global__ __launch_bounds__(256, 2) void k3_whiten(const float* __restrict__ x,
                                                    const float* __restrict__ lpad,
                                                    const float* __restrict__ nmu,
                                                    float* __restrict__ out) {
  __shared__ float Lw[32*580];   // 32 k-rows, stride 580 (16B-aligned, mod32==4)
  __shared__ float muL[32*32];   // [d][kl]
  const int t = threadIdx.x;
  const int bx = blockIdx.x;     // 0..511
  const int m = (bx >> 3) & 1;
  const int u = ((bx >> 4) << 3) | (bx & 7);   // 0..255
  const int ktile = ((u & 1) << 1) | m;        // 2p + m
  const int chunk = u >> 1;                    // 0..127
  const int k0 = ktile*32;

  {
    const f32x4* src = (const f32x4*)(lpad + (size_t)k0*576);
    #pragma unroll
    for (int q=0;q<18;q++){
      const int idx = t + q*256;        // 4608 f32x4 = 32 rows x 144
      const int row = idx/144, col = idx - row*144;
      *(f32x4*)(&Lw[row*580 + col*4]) = src[idx];
    }
    #pragma unroll
    for (int idx=t; idx<1024; idx+=256)
      muL[idx] = nmu[(idx>>5)*128 + k0 + (idx&31)];
  }
  __syncthreads();

  const int kl = t & 31;
  const int so = t >> 5;          // 0..7 sample slot
  const float* Lrow = &Lw[kl*580];
  const int b0 = chunk*128;

  for (int it=0; it<4; ++it) {
    const int base = b0 + it*32 + so;
    const float* xa = x + (size_t)(base     )*4096 + k0 + kl;
    const float* xb = x + (size_t)(base +  8)*4096 + k0 + kl;
    const float* xc = x + (size_t)(base + 16)*4096 + k0 + kl;
    const float* xd = x + (size_t)(base + 24)*4096 + k0 + kl;
    float vA[32], vB[32], vC[32], vD[32];
    #pragma unroll
    for (int d=0; d<32; ++d) vA[d] = xa[d*128];
    #pragma unroll
    for (int d=0; d<32; ++d) vB[d] = xb[d*128];
    #pragma unroll
    for (int d=0; d<32; ++d) vC[d] = xc[d*128];
    #pragma unroll
    for (int d=0; d<32; ++d) vD[d] = xd[d*128];
    #pragma unroll
    for (int d=0; d<32; ++d) {
      const float m2 = muL[d*32 + kl];
      vA[d] -= m2; vB[d] -= m2; vC[d] -= m2; vD[d] -= m2;
    }
    int rs = 0;
    #pragma unroll
    for (int d=0; d<32; ++d) {
      float sA = vA[d], sB = vB[d], sC = vC[d], sD = vD[d];
      const int nq = (d+3)>>2;
      #pragma unroll
      for (int q=0; q<nq; ++q) {
        const f32x4 Lq = *(const f32x4*)(Lrow + rs + 4*q);
        sA -= Lq[0]*vA[4*q+0] + Lq[1]*vA[4*q+1] + Lq[2]*vA[4*q+2] + Lq[3]*vA[4*q+3];
        sB -= Lq[0]*vB[4*q+0] + Lq[1]*vB[4*q+1] + Lq[2]*vB[4*q+2] + Lq[3]*vB[4*q+3];
        sC -= Lq[0]*vC[4*q+0] + Lq[1]*vC[4*q+1] + Lq[2]*vC[4*q+2] + Lq[3]*vC[4*q+3];
        sD -= Lq[0]*vD[4*q+0] + Lq[1]*vD[4*q+1] + Lq[2]*vD[4*q+2] + Lq[3]*vD[4*q+3];
      }
      const float di = Lrow[544+d];
      vA[d] = sA*di; vB[d] = sB*di; vC[d] = sC*di; vD[d] = sD*di;
      rs += 4*nq;
    }
    float* oa = out + (size_t)(base     )*4096 + k0 + kl;
    float* ob = out + (size_t)(base +  8)*4096 + k0 + kl;
    float* oc = out + (size_t)(base + 16)*4096 + k0 + kl;
    float* od = out + (size_t)(base + 24)*4096 + k0 + kl;
    #pragma unroll
    for (int d=0; d<32; ++d) __builtin_nontemporal_store(vA[d], oa + d*128);
    #pragma unroll
    for (int d=0; d<32; ++d) __builtin_nontemporal_store(vB[d], ob + d*128);
    #pragma unroll
    for (int d=0; d<32; ++d) __builtin_nontemporal_store(vC[d], oc + d*128);
    #pragma unroll
    for (int d=0; d<32; ++d) __builtin_nontemporal_store(vD[d], od + d*128);
  }
}

// ---------------------------------------------------------------------------
extern "C" void kernel_launch(void* const* d_in, const int* in_sizes, int n_in,
                              void* d_out, int out_size, void* d_ws, size_t ws_size,
                              hipStream_t stream) {
  const float* x   = (const float*)d_in[0];
  const float* mu0 = (const float*)d_in[1];
  const float* L0  = (const float*)d_in[2];
  const float* n0  = (const float*)d_in[3];
  float* out  = (float*)d_out;
  float* part = out;                    // [512][608][64] = 19,922,944 floats (scratch in d_out)
  float* sfin = out + 20971520;         // [2][608][128]  = 155,648 floats   (scratch in d_out)
  float* lpad = (float*)d_ws;           // [128][576]
  float* nmu  = lpad + 128*576;         // [32][128]

  k1_scatter<<<512, 256, 0, stream>>>(x, part);
  k2a_reduce<<<608, 256, 0, stream>>>(part, sfin);
  k2b_chol  <<<128, 256, 0, stream>>>(sfin, mu0, L0, n0, lpad, nmu);
  k3_whiten <<<512, 256, 0, stream>>>(x, lpad, nmu, out);
}

// Round 6
// 200.496 us; speedup vs baseline: 1.2947x; 1.1362x over previous
//
#include <hip/hip_runtime.h>

typedef __attribute__((ext_vector_type(4))) float f32x4;

#define NB 16384
#define ND 32
#define NK 128

// ---------------------------------------------------------------------------
// Kernel 1 (v3, LDS-free): raw per-cluster scatter M = sum_b x x^T
// (lower-tri, rect-packed 4-row strips) + column sums S, for a 64-k tile and
// a 64-sample chunk.  grid = 512 (ktile = bx&1, chunk = bx>>1), block = 256.
// Thread (kl = t&63, SP = t>>6) loads x[b][d][k0+kl] directly from global
// (stride-128 scalar loads; 64 lanes = 256B contiguous per instruction).
// The 4 waves of a block re-read the same 256B lines via L1/L2.
// No LDS, no barriers -> pure stream + register-FMA.
// Per-block partial layout: [608][64] floats at part + blockIdx*38912
//   vidx 0..575  : strips R=0..7, strip R at 8R(R+1), entry (r,c) = r*4(R+1)+c
//   vidx 576+d   : column sum for dim d
// Partials stored nontemporal (keep x resident in L3 for k3).
// ---------------------------------------------------------------------------
template<int SP>
__device__ __forceinline__ void k1_body(const float* __restrict__ x,
                                        float* __restrict__ part,
                                        int k0, int b0, int kl) {
  constexpr int CL = 4*(SP+1);   // cols of low strip  R=SP
  constexpr int CH = 4*(8-SP);   // cols of high strip R=7-SP  (CH >= CL)
  constexpr int NV = CH;         // x-values needed: v[0..CH-1]

  float aL[4][CL];
  float aH[4][CH];
  float ssum[8];
  #pragma unroll
  for (int r=0;r<4;r++){
    #pragma unroll
    for (int c=0;c<CL;c++) aL[r][c]=0.f;
    #pragma unroll
    for (int c=0;c<CH;c++) aH[r][c]=0.f;
  }
  #pragma unroll
  for (int i=0;i<8;i++) ssum[i]=0.f;

  const float* xp = x + (size_t)b0*4096 + k0 + kl;

  for (int s=0; s<64; ++s) {
    const float* xs = xp + (size_t)s*4096;
    float v[NV];
    #pragma unroll
    for (int d=0; d<NV; ++d) v[d] = xs[d*128];
    #pragma unroll
    for (int r=0;r<4;r++){ ssum[r] += v[4*SP+r]; ssum[4+r] += v[CH-4+r]; }
    #pragma unroll
    for (int r=0;r<4;r++){
      const float al = v[4*SP+r];      // row 4*SP+r
      #pragma unroll
      for (int c=0;c<CL;c++) aL[r][c] += al*v[c];
      const float ah = v[CH-4+r];      // row 4*(7-SP)+r
      #pragma unroll
      for (int c=0;c<CH;c++) aH[r][c] += ah*v[c];
    }
  }

  float* pb = part + (size_t)blockIdx.x*38912;
  #pragma unroll
  for (int r=0;r<4;r++){
    #pragma unroll
    for (int c=0;c<CL;c++)
      __builtin_nontemporal_store(aL[r][c], &pb[(8*SP*(SP+1) + r*CL + c)*64 + kl]);
    #pragma unroll
    for (int c=0;c<CH;c++)
      __builtin_nontemporal_store(aH[r][c], &pb[(8*(7-SP)*(8-SP) + r*CH + c)*64 + kl]);
  }
  #pragma unroll
  for (int r=0;r<4;r++){
    __builtin_nontemporal_store(ssum[r],   &pb[(576 + 4*SP + r)*64 + kl]);
    __builtin_nontemporal_store(ssum[4+r], &pb[(576 + CH-4 + r)*64 + kl]);
  }
}

__global__ __launch_bounds__(256, 2) void k1_scatter(const float* __restrict__ x,
                                                     float* __restrict__ part) {
  const int t = threadIdx.x;
  const int ktile = blockIdx.x & 1;
  const int chunk = blockIdx.x >> 1;     // 0..255
  const int k0 = ktile*64, b0 = chunk*64;
  const int kl = t & 63;
  switch (t>>6) {  // wave-uniform
    case 0:  k1_body<0>(x, part, k0, b0, kl); break;
    case 1:  k1_body<1>(x, part, k0, b0, kl); break;
    case 2:  k1_body<2>(x, part, k0, b0, kl); break;
    default: k1_body<3>(x, part, k0, b0, kl); break;
  }
}

// ---------------------------------------------------------------------------
// Kernel 2a: reduce 128-chunk halves of partials.  grid 608 (2 halves x 2
// ktiles x 152 vgroups), block 256.  Nontemporal loads (don't evict x in L3).
// k1 block for (ktile, chunk) is chunk*2 + ktile  ->  stride 2*38912 per chunk.
// out sfin[h][608][128]
// ---------------------------------------------------------------------------
__global__ void k2a_reduce(const float* __restrict__ part, float* __restrict__ sfin) {
  const int t = threadIdx.x;
  const int bx = blockIdx.x;
  const int h = bx & 1, ktile = (bx>>1)&1, vg = bx>>2;
  const int vidx = vg*4 + (t>>6);
  const int kl = t & 63;
  // chunks h*128 .. h*128+127 of this ktile
  const float* p = part + ((size_t)(h*128)*2 + ktile)*38912 + vidx*64 + kl;
  float a0=0.f,a1=0.f,a2=0.f,a3=0.f;
  for (int c=0;c<128;c+=4){
    a0 += __builtin_nontemporal_load(&p[(size_t)(c+0)*77824]);
    a1 += __builtin_nontemporal_load(&p[(size_t)(c+1)*77824]);
    a2 += __builtin_nontemporal_load(&p[(size_t)(c+2)*77824]);
    a3 += __builtin_nontemporal_load(&p[(size_t)(c+3)*77824]);
  }
  sfin[h*77824 + vidx*128 + ktile*64 + kl] = (a0+a1)+(a2+a3);
}

// ---------------------------------------------------------------------------
// Kernel 2b: per-cluster cov assembly + Cholesky.  grid 128, block 256.
// Writes row-padded L (rows padded to mult-of-4, zeros) + inv-diag to ws,
// and new_mu[d][K] to ws.
// ---------------------------------------------------------------------------
__global__ void k2b_chol(const float* __restrict__ sfin,
                         const float* __restrict__ mu0,
                         const float* __restrict__ L0,
                         const float* __restrict__ n0p,
                         float* __restrict__ lpad,
                         float* __restrict__ nmu) {
  const int k = blockIdx.x;
  const int t = threadIdx.x;
  __shared__ float L0s[32*33];
  __shared__ float Am[32*33];
  __shared__ float xdl[32];
  __shared__ float dinv[32];
  const float n0 = n0p[0];
  const float denom = n0 + (float)NB;

  for (int idx = t; idx < 1024; idx += 256)
    L0s[(idx>>5)*33 + (idx&31)] = L0[k*1024 + idx];
  if (t < 32) {
    const float S  = sfin[(576+t)*128 + k] + sfin[77824 + (576+t)*128 + k];
    const float m0 = mu0[t*128 + k];
    nmu[t*128 + k] = (n0*m0 + S) / denom;          // B*x_mu == S
    xdl[t] = S*(1.0f/NB) - m0;
  }
  __syncthreads();

  const float c1 = n0/denom, c2 = 1.0f/denom;
  const float c3 = n0*(float)NB/(denom*denom);
  for (int idx = t; idx < 1024; idx += 256) {
    const int d = idx>>5, e = idx&31;
    const int dd = d>=e?d:e, ee = d>=e?e:d;
    const int R = dd>>2;
    const int vi = 8*R*(R+1) + (dd&3)*4*(R+1) + ee;
    const float M  = sfin[vi*128 + k]      + sfin[77824 + vi*128 + k];
    const float Sd = sfin[(576+d)*128 + k] + sfin[77824 + (576+d)*128 + k];
    const float Se = sfin[(576+e)*128 + k] + sfin[77824 + (576+e)*128 + k];
    const float C = M - Sd*Se*(1.0f/NB);
    float g = 0.f;
    #pragma unroll 8
    for (int f=0; f<32; f++) g += L0s[d*33+f]*L0s[e*33+f];
    float a = g*c1 + C*c2 + xdl[d]*xdl[e]*c3;
    if (d==e) a += 1.0f;
    Am[d*33+e] = a;
  }
  __syncthreads();

  for (int j=0;j<32;j++){
    float acc = 0.f;
    if (t < 32 && t >= j) {
      acc = Am[t*33+j];
      for (int e=0;e<j;e++) acc -= Am[t*33+e]*Am[j*33+e];
    }
    __syncthreads();
    if (t == j) {
      const float dj = sqrtf(acc);
      Am[j*33+j] = dj;
      dinv[j] = 1.0f/dj;
    }
    __syncthreads();
    if (t < 32 && t > j) Am[t*33+j] = acc*dinv[j];
    __syncthreads();
  }

  if (t < 32) {
    const int d = t;
    int rs = 0;
    for (int e=0;e<d;e++) rs += (e+3)>>2;
    rs *= 4;
    const int rl = ((d+3)>>2)*4;
    float* lp = lpad + k*576;
    for (int e=0;e<rl;e++) lp[rs+e] = (e<d) ? Am[d*33+e] : 0.f;
    lp[544+d] = dinv[d];
  }
}

// ---------------------------------------------------------------------------
// Kernel 3: whitening solve z = L^{-1}(x - mu').  grid 512, block 256.
// Block = 32-k tile x 128 samples; kl = t&31 -> every load/store covers full
// 128B lines.  XCD swizzle: ktile pair (2p, 2p+1) of the same chunk shares
// each 256B fetch granule -> both members placed on the SAME XCD.
// Output written with nontemporal stores (no L2/L3 allocate).
// ---------------------------------------------------------------------------
__global__ __launch_bounds__(256, 2) void k3_whiten(const float* __restrict__ x,
                                                    const float* __restrict__ lpad,
                                                    const float* __restrict__ nmu,
                                                    float* __restrict__ out) {
  __shared__ float Lw[32*580];   // 32 k-rows, stride 580 (16B-aligned, mod32==4)
  __shared__ float muL[32*32];   // [d][kl]
  const int t = threadIdx.x;
  const int bx = blockIdx.x;     // 0..511
  const int m = (bx >> 3) & 1;
  const int u = ((bx >> 4) << 3) | (bx & 7);   // 0..255
  const int ktile = ((u & 1) << 1) | m;        // 2p + m
  const int chunk = u >> 1;                    // 0..127
  const int k0 = ktile*32;

  {
    const f32x4* src = (const f32x4*)(lpad + (size_t)k0*576);
    #pragma unroll
    for (int q=0;q<18;q++){
      const int idx = t + q*256;        // 4608 f32x4 = 32 rows x 144
      const int row = idx/144, col = idx - row*144;
      *(f32x4*)(&Lw[row*580 + col*4]) = src[idx];
    }
    #pragma unroll
    for (int idx=t; idx<1024; idx+=256)
      muL[idx] = nmu[(idx>>5)*128 + k0 + (idx&31)];
  }
  __syncthreads();

  const int kl = t & 31;
  const int so = t >> 5;          // 0..7 sample slot
  const float* Lrow = &Lw[kl*580];
  const int b0 = chunk*128;

  for (int it=0; it<4; ++it) {
    const int base = b0 + it*32 + so;
    const float* xa = x + (size_t)(base     )*4096 + k0 + kl;
    const float* xb = x + (size_t)(base +  8)*4096 + k0 + kl;
    const float* xc = x + (size_t)(base + 16)*4096 + k0 + kl;
    const float* xd = x + (size_t)(base + 24)*4096 + k0 + kl;
    float vA[32], vB[32], vC[32], vD[32];
    #pragma unroll
    for (int d=0; d<32; ++d) vA[d] = xa[d*128];
    #pragma unroll
    for (int d=0; d<32; ++d) vB[d] = xb[d*128];
    #pragma unroll
    for (int d=0; d<32; ++d) vC[d] = xc[d*128];
    #pragma unroll
    for (int d=0; d<32; ++d) vD[d] = xd[d*128];
    #pragma unroll
    for (int d=0; d<32; ++d) {
      const float m2 = muL[d*32 + kl];
      vA[d] -= m2; vB[d] -= m2; vC[d] -= m2; vD[d] -= m2;
    }
    int rs = 0;
    #pragma unroll
    for (int d=0; d<32; ++d) {
      float sA = vA[d], sB = vB[d], sC = vC[d], sD = vD[d];
      const int nq = (d+3)>>2;
      #pragma unroll
      for (int q=0; q<nq; ++q) {
        const f32x4 Lq = *(const f32x4*)(Lrow + rs + 4*q);
        sA -= Lq[0]*vA[4*q+0] + Lq[1]*vA[4*q+1] + Lq[2]*vA[4*q+2] + Lq[3]*vA[4*q+3];
        sB -= Lq[0]*vB[4*q+0] + Lq[1]*vB[4*q+1] + Lq[2]*vB[4*q+2] + Lq[3]*vB[4*q+3];
        sC -= Lq[0]*vC[4*q+0] + Lq[1]*vC[4*q+1] + Lq[2]*vC[4*q+2] + Lq[3]*vC[4*q+3];
        sD -= Lq[0]*vD[4*q+0] + Lq[1]*vD[4*q+1] + Lq[2]*vD[4*q+2] + Lq[3]*vD[4*q+3];
      }
      const float di = Lrow[544+d];
      vA[d] = sA*di; vB[d] = sB*di; vC[d] = sC*di; vD[d] = sD*di;
      rs += 4*nq;
    }
    float* oa = out + (size_t)(base     )*4096 + k0 + kl;
    float* ob = out + (size_t)(base +  8)*4096 + k0 + kl;
    float* oc = out + (size_t)(base + 16)*4096 + k0 + kl;
    float* od = out + (size_t)(base + 24)*4096 + k0 + kl;
    #pragma unroll
    for (int d=0; d<32; ++d) __builtin_nontemporal_store(vA[d], oa + d*128);
    #pragma unroll
    for (int d=0; d<32; ++d) __builtin_nontemporal_store(vB[d], ob + d*128);
    #pragma unroll
    for (int d=0; d<32; ++d) __builtin_nontemporal_store(vC[d], oc + d*128);
    #pragma unroll
    for (int d=0; d<32; ++d) __builtin_nontemporal_store(vD[d], od + d*128);
  }
}

// ---------------------------------------------------------------------------
extern "C" void kernel_launch(void* const* d_in, const int* in_sizes, int n_in,
                              void* d_out, int out_size, void* d_ws, size_t ws_size,
                              hipStream_t stream) {
  const float* x   = (const float*)d_in[0];
  const float* mu0 = (const float*)d_in[1];
  const float* L0  = (const float*)d_in[2];
  const float* n0  = (const float*)d_in[3];
  float* out  = (float*)d_out;
  float* part = out;                    // [512][608][64] = 19,922,944 floats (scratch in d_out)
  float* sfin = out + 20971520;         // [2][608][128]  = 155,648 floats   (scratch in d_out)
  float* lpad = (float*)d_ws;           // [128][576]
  float* nmu  = lpad + 128*576;         // [32][128]

  k1_scatter<<<512, 256, 0, stream>>>(x, part);
  k2a_reduce<<<608, 256, 0, stream>>>(part, sfin);
  k2b_chol  <<<128, 256, 0, stream>>>(sfin, mu0, L0, n0, lpad, nmu);
  k3_whiten <<<512, 256, 0, stream>>>(x, lpad, nmu, out);
}